// Round 2
// baseline (1319.966 us; speedup 1.0000x reference)
//
#include <hip/hip_runtime.h>
#include <math.h>

// Problem constants
#define NROWS (32 * 4096)   // N*S = 131072
#define VDIM 128
#define KCODES 512
// tn = 0.06 * sqrt(128)
#define TN 0.67882250993908565f

// Normalize embedding codes: embn[k][v] = tn * emb0[k][v] / ||emb0[k]||, e2[k] = sum embn^2
__global__ void prep_emb(const float* __restrict__ emb0,
                         float* __restrict__ embn,
                         float* __restrict__ e2) {
    int k = blockIdx.x;       // KCODES blocks
    int l = threadIdx.x;      // 64 threads = 1 wave
    const float* row = emb0 + (size_t)k * VDIM;
    float a = row[l];
    float b = row[l + 64];
    float ss = a * a + b * b;
    #pragma unroll
    for (int off = 32; off; off >>= 1) ss += __shfl_xor(ss, off);
    float nrm = sqrtf(ss);
    float ea = (TN * a) / nrm;
    float eb = (TN * b) / nrm;
    embn[(size_t)k * VDIM + l] = ea;
    embn[(size_t)k * VDIM + l + 64] = eb;
    float s2 = ea * ea + eb * eb;
    #pragma unroll
    for (int off = 32; off; off >>= 1) s2 += __shfl_xor(s2, off);
    if (l == 0) e2[k] = s2;
}

// Main: one thread per row. x0 row in registers, scan all 512 codes.
__launch_bounds__(256)
__global__ void vq_main(const float* __restrict__ x0,
                        const float* __restrict__ embn,
                        const float* __restrict__ e2,
                        unsigned* __restrict__ hist,
                        float* __restrict__ out0,
                        float* __restrict__ out1,
                        float* __restrict__ out2) {
    int row = blockIdx.x * blockDim.x + threadIdx.x;

    const float4* xp = (const float4*)(x0 + (size_t)row * VDIM);
    float4 xr[32];
    #pragma unroll
    for (int j = 0; j < 32; j++) xr[j] = xp[j];

    // ||x0||^2 with 4-way split accumulation
    float n0 = 0.f, n1 = 0.f, n2 = 0.f, n3 = 0.f;
    #pragma unroll
    for (int j = 0; j < 32; j++) {
        n0 = fmaf(xr[j].x, xr[j].x, n0);
        n1 = fmaf(xr[j].y, xr[j].y, n1);
        n2 = fmaf(xr[j].z, xr[j].z, n2);
        n3 = fmaf(xr[j].w, xr[j].w, n3);
    }
    float n0sq = (n0 + n1) + (n2 + n3);
    float nrm = sqrtf(n0sq);
    float s = TN / nrm;           // x[v] = (TN*x0[v])/nrm = s*x0[v]
    float x2 = s * s * n0sq;      // ||x||^2, constant over k

    float bestd = INFINITY;
    int besti = 0;
    for (int k = 0; k < KCODES; k++) {
        const float4* ep = (const float4*)(embn + (size_t)k * VDIM);
        float d0 = 0.f, d1 = 0.f, d2a = 0.f, d3 = 0.f;
        #pragma unroll
        for (int j = 0; j < 32; j++) {
            float4 e = ep[j];   // wave-uniform address -> scalar loads
            d0  = fmaf(xr[j].x, e.x, d0);
            d1  = fmaf(xr[j].y, e.y, d1);
            d2a = fmaf(xr[j].z, e.z, d2a);
            d3  = fmaf(xr[j].w, e.w, d3);
        }
        float dot  = (d0 + d1) + (d2a + d3);  // dot(x0, e); dot(x, e) = s*dot
        float dist = (x2 + e2[k]) - 2.0f * (s * dot);
        if (dist < bestd) { bestd = dist; besti = k; }   // first-min tie-break
    }

    // Epilogue: gather winning code, emit out0/out1/out2 (fp32), hist
    const float4* ebp = (const float4*)(embn + (size_t)besti * VDIM);
    float4* o0 = (float4*)(out0 + (size_t)row * VDIM);
    float s1 = 0.f, sq = 0.f;
    #pragma unroll
    for (int j = 0; j < 32; j++) {
        float4 xa = xr[j];
        float4 e  = ebp[j];
        float4 o;
        float xx, dxe, dx0;
        xx = s * xa.x; o.x = (e.x - xx) + xx;
        dxe = xx - e.x; s1 = fmaf(dxe, dxe, s1);
        dx0 = xx - xa.x; sq = fmaf(dx0, dx0, sq);
        xx = s * xa.y; o.y = (e.y - xx) + xx;
        dxe = xx - e.y; s1 = fmaf(dxe, dxe, s1);
        dx0 = xx - xa.y; sq = fmaf(dx0, dx0, sq);
        xx = s * xa.z; o.z = (e.z - xx) + xx;
        dxe = xx - e.z; s1 = fmaf(dxe, dxe, s1);
        dx0 = xx - xa.z; sq = fmaf(dx0, dx0, sq);
        xx = s * xa.w; o.w = (e.w - xx) + xx;
        dxe = xx - e.w; s1 = fmaf(dxe, dxe, s1);
        dx0 = xx - xa.w; sq = fmaf(dx0, dx0, sq);
        o0[j] = o;
    }
    out1[row] = s1;
    out2[row] = s1 + sq;
    atomicAdd(&hist[besti], 1u);
}

__global__ void entropy_k(const unsigned* __restrict__ hist,
                          float* __restrict__ out) {
    __shared__ float red[8];
    int t = threadIdx.x;   // KCODES threads
    float h = (float)hist[t];
    float p = h / (float)NROWS;
    float term = (h > 0.f) ? p * logf(p) : 0.f;
    #pragma unroll
    for (int off = 32; off; off >>= 1) term += __shfl_xor(term, off);
    if ((t & 63) == 0) red[t >> 6] = term;
    __syncthreads();
    if (t == 0) {
        float ssum = 0.f;
        #pragma unroll
        for (int i = 0; i < 8; i++) ssum += red[i];
        out[0] = -ssum;
    }
}

extern "C" void kernel_launch(void* const* d_in, const int* in_sizes, int n_in,
                              void* d_out, int out_size, void* d_ws, size_t ws_size,
                              hipStream_t stream) {
    const float* x0   = (const float*)d_in[0];
    const float* emb0 = (const float*)d_in[1];

    float* embn = (float*)d_ws;                       // 512*128 floats = 256 KB
    float* e2   = embn + (size_t)KCODES * VDIM;       // 512 floats
    unsigned* hist = (unsigned*)(e2 + KCODES);        // 512 uints

    float* out  = (float*)d_out;
    float* out0 = out;
    float* out1 = out0 + (size_t)NROWS * VDIM;
    float* out2 = out1 + NROWS;
    float* oent = out2 + NROWS;

    hipMemsetAsync(hist, 0, KCODES * sizeof(unsigned), stream);
    prep_emb<<<KCODES, 64, 0, stream>>>(emb0, embn, e2);
    vq_main<<<NROWS / 256, 256, 0, stream>>>(x0, embn, e2, hist, out0, out1, out2);
    entropy_k<<<1, KCODES, 0, stream>>>(hist, oent);
}

// Round 3
// 193.993 us; speedup vs baseline: 6.8042x; 6.8042x over previous
//
#include <hip/hip_runtime.h>
#include <math.h>

// Problem constants
#define VDIM   128
#define KCODES 512
#define NROWS  (32 * 4096)      // 131072
#define TILE_ROWS 256           // rows per block (4 waves x 64 rows)
#define TN 0.67882250993908565f // 0.06 * sqrt(128)

typedef __attribute__((ext_vector_type(8))) short bf16x8;  // MFMA A/B frag (4 VGPR)
typedef __attribute__((ext_vector_type(4))) float f32x4;   // MFMA C/D frag

__device__ __forceinline__ unsigned short f2bf(float f) {
    unsigned u = __float_as_uint(f);
    unsigned r = u + 0x7FFFu + ((u >> 16) & 1u);   // round-to-nearest-even
    return (unsigned short)(r >> 16);
}

__device__ __forceinline__ bf16x8 pack8(float4 a, float4 b) {
    bf16x8 v;
    v[0] = (short)f2bf(a.x); v[1] = (short)f2bf(a.y);
    v[2] = (short)f2bf(a.z); v[3] = (short)f2bf(a.w);
    v[4] = (short)f2bf(b.x); v[5] = (short)f2bf(b.y);
    v[6] = (short)f2bf(b.z); v[7] = (short)f2bf(b.w);
    return v;
}

// Normalize codes: embn fp32 (for out0 gather), ebf bf16 (MFMA B), e2 = ||e||^2
__global__ void prep_emb(const float* __restrict__ emb0,
                         float* __restrict__ embn,
                         unsigned short* __restrict__ ebf,
                         float* __restrict__ e2) {
    int k = blockIdx.x;       // KCODES blocks
    int l = threadIdx.x;      // 64 threads = 1 wave
    const float* row = emb0 + (size_t)k * VDIM;
    float a = row[l];
    float b = row[l + 64];
    float ss = a * a + b * b;
    #pragma unroll
    for (int off = 32; off; off >>= 1) ss += __shfl_xor(ss, off);
    float nrm = sqrtf(ss);
    float ea = (TN * a) / nrm;
    float eb = (TN * b) / nrm;
    embn[(size_t)k * VDIM + l]      = ea;
    embn[(size_t)k * VDIM + l + 64] = eb;
    ebf[(size_t)k * VDIM + l]      = f2bf(ea);
    ebf[(size_t)k * VDIM + l + 64] = f2bf(eb);
    float s2 = ea * ea + eb * eb;
    #pragma unroll
    for (int off = 32; off; off >>= 1) s2 += __shfl_xor(s2, off);
    if (l == 0) e2[k] = s2;
}

// Main: per wave, 4 row-strips of 16 (A frags in VGPRs); scan 512 codes via
// bf16 MFMA with B frags loaded straight from the L2-resident code table.
// argmin(dist) == argmax(dot(x0, e)) since ||x|| and ||e|| are constant.
__global__ __launch_bounds__(256) void vq_main(
        const float* __restrict__ x0,
        const unsigned short* __restrict__ ebf,
        const float* __restrict__ embn,
        const float* __restrict__ e2,
        unsigned* __restrict__ hist,
        float* __restrict__ out0,
        float* __restrict__ out1,
        float* __restrict__ out2) {
    int t = threadIdx.x;
    int w = t >> 6;           // wave 0..3
    int l = t & 63;
    int n15 = l & 15;         // MFMA row/col-within-16 (A: m, B: n, C: col)
    int q = l >> 4;           // quad: k = q*8 + j

    // ---- Load A: 4 strips x 16 rows, K=128 as 4 k-chunks; fp32 -> bf16 frags
    int rowbase = blockIdx.x * TILE_ROWS + (w << 6);
    bf16x8 afr[4][4];
    float nsq[4];
    #pragma unroll
    for (int s = 0; s < 4; ++s) {
        const float* xrow = x0 + (size_t)(rowbase + (s << 4) + n15) * VDIM + (q << 3);
        float p0 = 0.f, p1 = 0.f;
        #pragma unroll
        for (int kc = 0; kc < 4; ++kc) {
            const float4* xp = (const float4*)(xrow + (kc << 5));
            float4 a = xp[0], b = xp[1];
            p0 = fmaf(a.x, a.x, p0); p1 = fmaf(a.y, a.y, p1);
            p0 = fmaf(a.z, a.z, p0); p1 = fmaf(a.w, a.w, p1);
            p0 = fmaf(b.x, b.x, p0); p1 = fmaf(b.y, b.y, p1);
            p0 = fmaf(b.z, b.z, p0); p1 = fmaf(b.w, b.w, p1);
            afr[s][kc] = pack8(a, b);
        }
        nsq[s] = p0 + p1;
    }
    #pragma unroll
    for (int s = 0; s < 4; ++s) {           // reduce ||x0||^2 across quads
        nsq[s] += __shfl_xor(nsq[s], 16, 64);
        nsq[s] += __shfl_xor(nsq[s], 32, 64);
    }

    // ---- N-loop: 32 chunks of 16 codes; running argmax of dot
    float best[4][4];
    int   bidx[4][4];
    #pragma unroll
    for (int s = 0; s < 4; ++s)
        #pragma unroll
        for (int r = 0; r < 4; ++r) { best[s][r] = -3.4e38f; bidx[s][r] = 0; }

    const f32x4 zero4 = {0.f, 0.f, 0.f, 0.f};
    const bf16x8* eb8 = (const bf16x8*)ebf;   // code row = 16 frag slots
    for (int cn = 0; cn < 32; ++cn) {
        int n = (cn << 4) | n15;              // this lane's code (C col = lane&15)
        const bf16x8* bp = eb8 + (size_t)n * 16 + q;   // slot = kc*4 + q
        bf16x8 b0 = bp[0], b1 = bp[4], b2 = bp[8], b3 = bp[12];
        #pragma unroll
        for (int s = 0; s < 4; ++s) {
            f32x4 acc = __builtin_amdgcn_mfma_f32_16x16x32_bf16(afr[s][0], b0, zero4, 0, 0, 0);
            acc = __builtin_amdgcn_mfma_f32_16x16x32_bf16(afr[s][1], b1, acc, 0, 0, 0);
            acc = __builtin_amdgcn_mfma_f32_16x16x32_bf16(afr[s][2], b2, acc, 0, 0, 0);
            acc = __builtin_amdgcn_mfma_f32_16x16x32_bf16(afr[s][3], b3, acc, 0, 0, 0);
            #pragma unroll
            for (int r = 0; r < 4; ++r) {
                float d = acc[r];
                if (d > best[s][r]) { best[s][r] = d; bidx[s][r] = n; }
            }
        }
    }

    // ---- Reduce argmax across the 16 lanes holding the same row (cols)
    #pragma unroll
    for (int m = 1; m <= 8; m <<= 1) {
        #pragma unroll
        for (int s = 0; s < 4; ++s)
            #pragma unroll
            for (int r = 0; r < 4; ++r) {
                float ov = __shfl_xor(best[s][r], m, 64);
                int   oi = __shfl_xor(bidx[s][r], m, 64);
                if (ov > best[s][r] || (ov == best[s][r] && oi < bidx[s][r])) {
                    best[s][r] = ov; bidx[s][r] = oi;
                }
            }
    }

    // ---- Stage per-row results to (small) LDS for the coalesced epilogue
    __shared__ int   sbesti[TILE_ROWS];
    __shared__ float sdot[TILE_ROWS];
    __shared__ float sn0[TILE_ROWS];
    if (n15 == 0) {
        #pragma unroll
        for (int s = 0; s < 4; ++s)
            #pragma unroll
            for (int r = 0; r < 4; ++r) {
                int lr = (w << 6) + (s << 4) + (q << 2) + r;  // C row = q*4+r
                sbesti[lr] = bidx[s][r];
                sdot[lr]   = best[s][r];
            }
    }
    if (q == 0) {
        #pragma unroll
        for (int s = 0; s < 4; ++s) sn0[(w << 6) + (s << 4) + n15] = nsq[s];
    }
    __syncthreads();

    // ---- Epilogue: one row per thread
    {
        int lr = t;
        size_t row = (size_t)blockIdx.x * TILE_ROWS + lr;
        int bi = sbesti[lr];
        float dotv = sdot[lr];
        float nn = sn0[lr];
        float sc = TN / sqrtf(nn);                 // x = sc * x0
        const float4* ep4 = (const float4*)(embn + (size_t)bi * VDIM);
        float4* op4 = (float4*)(out0 + row * (size_t)VDIM);
        #pragma unroll
        for (int i = 0; i < 32; ++i) op4[i] = ep4[i];   // out0 = e[besti]
        float o1 = TN * TN + e2[bi] - 2.f * sc * dotv;  // sum (x-e)^2
        out1[row] = o1;
        float sm = sc - 1.f;
        out2[row] = o1 + sm * sm * nn;                  // + sum (x-x0)^2
        atomicAdd(&hist[bi], 1u);
    }
}

__global__ void entropy_k(const unsigned* __restrict__ hist,
                          float* __restrict__ out) {
    __shared__ float red[8];
    int t = threadIdx.x;   // KCODES threads
    float h = (float)hist[t];
    float p = h / (float)NROWS;
    float term = (h > 0.f) ? p * logf(p) : 0.f;
    #pragma unroll
    for (int off = 32; off; off >>= 1) term += __shfl_xor(term, off);
    if ((t & 63) == 0) red[t >> 6] = term;
    __syncthreads();
    if (t == 0) {
        float ssum = 0.f;
        #pragma unroll
        for (int i = 0; i < 8; i++) ssum += red[i];
        out[0] = -ssum;
    }
}

extern "C" void kernel_launch(void* const* d_in, const int* in_sizes, int n_in,
                              void* d_out, int out_size, void* d_ws, size_t ws_size,
                              hipStream_t stream) {
    const float* x0   = (const float*)d_in[0];
    const float* emb0 = (const float*)d_in[1];

    float* embn = (float*)d_ws;                              // 512*128 f32 = 256 KB
    float* e2   = embn + (size_t)KCODES * VDIM;              // 512 f32
    unsigned* hist = (unsigned*)(e2 + KCODES);               // 512 u32
    unsigned short* ebf = (unsigned short*)(hist + KCODES);  // 512*128 bf16 = 128 KB

    float* out  = (float*)d_out;
    float* out0 = out;
    float* out1 = out0 + (size_t)NROWS * VDIM;
    float* out2 = out1 + NROWS;
    float* oent = out2 + NROWS;

    hipMemsetAsync(hist, 0, KCODES * sizeof(unsigned), stream);
    prep_emb<<<KCODES, 64, 0, stream>>>(emb0, embn, ebf, e2);
    vq_main<<<NROWS / TILE_ROWS, 256, 0, stream>>>(x0, ebf, embn, e2, hist,
                                                   out0, out1, out2);
    entropy_k<<<1, KCODES, 0, stream>>>(hist, oent);
}